// Round 1
// baseline (2227.442 us; speedup 1.0000x reference)
//
#include <hip/hip_runtime.h>

// Sizes fixed by the reference problem.
#define NN 16384
#define CC 512
#define EE 524288
#define BB 64
#define HH 8
#define EFD 16

// ---------------- init / edge pre-pass ----------------

__global__ void init_kernel(float* deg, int* cnt_dst, int* cnt_src, int* gcnt) {
  int i = blockIdx.x * 256 + threadIdx.x;
  if (i < NN) { deg[i] = 1.0f; cnt_dst[i] = 0; cnt_src[i] = 0; }
  if (i < BB) gcnt[i] = 0;
}

__global__ void edge_pass1(const float* __restrict__ ea, const int* __restrict__ src,
                           const int* __restrict__ dst, float* __restrict__ ew,
                           float* deg, int* cnt_dst, int* cnt_src) {
  int e = blockIdx.x * 256 + threadIdx.x;
  if (e >= EE) return;
  const float4* p = (const float4*)(ea + (size_t)e * EFD);
  float s = 0.f;
#pragma unroll
  for (int i = 0; i < 4; ++i) {
    float4 v = p[i];
    s += v.x * v.x + v.y * v.y + v.z * v.z + v.w * v.w;
  }
  float w = sqrtf(s);
  ew[e] = w;
  atomicAdd(&deg[dst[e]], w);
  atomicAdd(&cnt_dst[dst[e]], 1);
  atomicAdd(&cnt_src[src[e]], 1);
}

__global__ void node_pass(const float* __restrict__ deg, float* __restrict__ dinv,
                          const int* __restrict__ batch, int* gcnt) {
  int i = blockIdx.x * 256 + threadIdx.x;
  if (i >= NN) return;
  float d = deg[i];
  dinv[i] = d > 0.f ? rsqrtf(fmaxf(d, 1e-12f)) : 0.f;
  atomicAdd(&gcnt[batch[i]], 1);
}

// exclusive scan of n<=16384 ints, single block of 1024 threads (16/thread)
__global__ __launch_bounds__(1024) void exscan_kernel(const int* __restrict__ cnt,
                                                      int* __restrict__ start,
                                                      int* __restrict__ cur, int n) {
  __shared__ int sums[1024];
  int tid = threadIdx.x;
  int base = tid * 16;
  int loc[16];
  int s = 0;
#pragma unroll
  for (int k = 0; k < 16; ++k) {
    int idx = base + k;
    int v = (idx < n) ? cnt[idx] : 0;
    loc[k] = v;
    s += v;
  }
  sums[tid] = s;
  __syncthreads();
  for (int off = 1; off < 1024; off <<= 1) {
    int v = (tid >= off) ? sums[tid - off] : 0;
    __syncthreads();
    sums[tid] += v;
    __syncthreads();
  }
  int pre = (tid == 0) ? 0 : sums[tid - 1];
#pragma unroll
  for (int k = 0; k < 16; ++k) {
    int idx = base + k;
    if (idx < n) { start[idx] = pre; cur[idx] = pre; pre += loc[k]; }
  }
  if (tid == 1023) start[n] = pre;
}

__global__ void gscan_kernel(const int* __restrict__ gcnt, int* __restrict__ gstart) {
  if (threadIdx.x == 0) {
    int s = 0;
    for (int b = 0; b < BB; ++b) { gstart[b] = s; s += gcnt[b]; }
  }
}

__global__ void fill_kernel(const int* __restrict__ src, const int* __restrict__ dst,
                            int* cur_dst, int* cur_src, int* __restrict__ elist_dst,
                            int* __restrict__ elist_src) {
  int e = blockIdx.x * 256 + threadIdx.x;
  if (e >= EE) return;
  int pd = atomicAdd(&cur_dst[dst[e]], 1);
  elist_dst[pd] = e;
  int ps = atomicAdd(&cur_src[src[e]], 1);
  elist_src[ps] = e;
}

// ---------------- GCN conv gather (CSR by dst) ----------------
// x_conv[i] = dinv[i]^2*xw[i] + sum_{e: dst=i} dinv[src]*ew*dinv[i]*xw[src] + gcn_b
__global__ __launch_bounds__(256) void xconv_kernel(
    const float* __restrict__ xw, const float* __restrict__ ew,
    const float* __restrict__ dinv, const int* __restrict__ src,
    const int* __restrict__ elist, const int* __restrict__ start,
    const float* __restrict__ gcn_b, float* __restrict__ xconv) {
  int i = blockIdx.x;
  int tid = threadIdx.x;
  int st = start[i], en = start[i + 1];
  float di = dinv[i];
  int c0 = tid * 2;
  __shared__ int sS[256];
  __shared__ float cS[256];
  float2 xv = *(const float2*)(xw + (size_t)i * CC + c0);
  float sc = di * di;
  float a0 = sc * xv.x + gcn_b[c0];
  float a1 = sc * xv.y + gcn_b[c0 + 1];
  for (int p0 = st; p0 < en; p0 += 256) {
    int m = min(256, en - p0);
    __syncthreads();
    if (tid < m) {
      int e = elist[p0 + tid];
      int sn = src[e];
      sS[tid] = sn;
      cS[tid] = dinv[sn] * ew[e] * di;
    }
    __syncthreads();
    for (int j = 0; j < m; ++j) {
      int sn = sS[j];
      float coef = cS[j];
      float2 v = *(const float2*)(xw + (size_t)sn * CC + c0);
      a0 += coef * v.x;
      a1 += coef * v.y;
    }
  }
  *(float2*)(xconv + (size_t)i * CC + c0) = make_float2(a0, a1);
}

// ---------------- edge projection scatter (CSR by src) ----------------
// ef[i] = sum_{e: src=i} relu(edge_attr[e] @ ep_w + ep_b)
__global__ __launch_bounds__(256) void ef_kernel(
    const float* __restrict__ ea, const float* __restrict__ ep_w,
    const float* __restrict__ ep_b, const int* __restrict__ elist,
    const int* __restrict__ start, float* __restrict__ ef) {
  int tid = threadIdx.x;
  int c0 = tid * 2;
  float w0[16], w1[16];
#pragma unroll
  for (int k = 0; k < 16; ++k) {
    w0[k] = ep_w[k * CC + c0];
    w1[k] = ep_w[k * CC + c0 + 1];
  }
  float b0 = ep_b[c0], b1 = ep_b[c0 + 1];
  __shared__ float eaS[16][16];
  for (int ni = 0; ni < 8; ++ni) {
    int node = blockIdx.x * 8 + ni;
    int st = start[node], en = start[node + 1];
    float a0 = 0.f, a1 = 0.f;
    for (int p0 = st; p0 < en; p0 += 16) {
      int m = min(16, en - p0);
      __syncthreads();
      if (tid < m * 16) {
        int el = tid >> 4, ft = tid & 15;
        eaS[el][ft] = ea[(size_t)elist[p0 + el] * EFD + ft];
      }
      __syncthreads();
      for (int j = 0; j < m; ++j) {
        float t0 = b0, t1 = b1;
#pragma unroll
        for (int k = 0; k < 16; ++k) {
          float a = eaS[j][k];
          t0 += a * w0[k];
          t1 += a * w1[k];
        }
        a0 += fmaxf(t0, 0.f);
        a1 += fmaxf(t1, 0.f);
      }
    }
    ef[(size_t)node * CC + c0] = a0;
    ef[(size_t)node * CC + c0 + 1] = a1;
  }
}

// ---------------- generic f32 tiled GEMM: C = A(MxK) @ B(KxN) ----------------
// ACT: 0=none 1=silu ; ACC: accumulate into existing C
template <int ACT, bool ACC>
__global__ __launch_bounds__(256) void gemm_kernel(const float* __restrict__ A,
                                                   const float* __restrict__ B,
                                                   const float* __restrict__ bias,
                                                   float* __restrict__ C, int M, int N,
                                                   int K) {
  __shared__ __align__(16) float As[16][68];
  __shared__ __align__(16) float Bs[16][68];
  int tid = threadIdx.x;
  int col0 = blockIdx.x * 64;
  int row0 = blockIdx.y * 64;
  int tx = tid & 15, ty = tid >> 4;
  int arow = tid >> 2, akq = (tid & 3) * 4;
  int bk = tid >> 4, bm = (tid & 15) * 4;
  float acc[4][4];
#pragma unroll
  for (int i = 0; i < 4; ++i)
#pragma unroll
    for (int j = 0; j < 4; ++j) acc[i][j] = 0.f;
  for (int k0 = 0; k0 < K; k0 += 16) {
    float4 a4 = *(const float4*)(A + (size_t)(row0 + arow) * K + k0 + akq);
    float4 b4 = *(const float4*)(B + (size_t)(k0 + bk) * N + col0 + bm);
    As[akq + 0][arow] = a4.x;
    As[akq + 1][arow] = a4.y;
    As[akq + 2][arow] = a4.z;
    As[akq + 3][arow] = a4.w;
    *(float4*)(&Bs[bk][bm]) = b4;
    __syncthreads();
#pragma unroll
    for (int kk = 0; kk < 16; ++kk) {
      float4 av = *(const float4*)(&As[kk][ty * 4]);
      float4 bv = *(const float4*)(&Bs[kk][tx * 4]);
      acc[0][0] += av.x * bv.x; acc[0][1] += av.x * bv.y;
      acc[0][2] += av.x * bv.z; acc[0][3] += av.x * bv.w;
      acc[1][0] += av.y * bv.x; acc[1][1] += av.y * bv.y;
      acc[1][2] += av.y * bv.z; acc[1][3] += av.y * bv.w;
      acc[2][0] += av.z * bv.x; acc[2][1] += av.z * bv.y;
      acc[2][2] += av.z * bv.z; acc[2][3] += av.z * bv.w;
      acc[3][0] += av.w * bv.x; acc[3][1] += av.w * bv.y;
      acc[3][2] += av.w * bv.z; acc[3][3] += av.w * bv.w;
    }
    __syncthreads();
  }
#pragma unroll
  for (int i = 0; i < 4; ++i) {
    int row = row0 + ty * 4 + i;
    float* cp = C + (size_t)row * N + col0 + tx * 4;
    float4 v = make_float4(acc[i][0], acc[i][1], acc[i][2], acc[i][3]);
    if (bias) {
      const float* bp = bias + col0 + tx * 4;
      v.x += bp[0]; v.y += bp[1]; v.z += bp[2]; v.w += bp[3];
    }
    if (ACC) {
      float4 o = *(const float4*)cp;
      v.x += o.x; v.y += o.y; v.z += o.z; v.w += o.w;
    }
    if (ACT == 1) {
      v.x = v.x / (1.f + __expf(-v.x));
      v.y = v.y / (1.f + __expf(-v.y));
      v.z = v.z / (1.f + __expf(-v.z));
      v.w = v.w / (1.f + __expf(-v.w));
    }
    *(float4*)cp = v;
  }
}

// ---------------- layernorm fused kernels ----------------

__device__ inline void block_reduce2(float& s, float& q, float* red) {
#pragma unroll
  for (int off = 32; off >= 1; off >>= 1) {
    s += __shfl_xor(s, off, 64);
    q += __shfl_xor(q, off, 64);
  }
  int wid = threadIdx.x >> 6;
  if ((threadIdx.x & 63) == 0) { red[wid * 2] = s; red[wid * 2 + 1] = q; }
  __syncthreads();
  s = red[0] + red[2] + red[4] + red[6];
  q = red[1] + red[3] + red[5] + red[7];
}

// out = LN(A + B) * g + be
__global__ __launch_bounds__(256) void ln_add_kernel(const float* __restrict__ A,
                                                     const float* __restrict__ Bb,
                                                     const float* __restrict__ g,
                                                     const float* __restrict__ be,
                                                     float* __restrict__ out) {
  int row = blockIdx.x, tid = threadIdx.x, c0 = tid * 2;
  __shared__ float red[8];
  float2 a = *(const float2*)(A + (size_t)row * CC + c0);
  float2 b = *(const float2*)(Bb + (size_t)row * CC + c0);
  float x0 = a.x + b.x, x1 = a.y + b.y;
  float s = x0 + x1, q = x0 * x0 + x1 * x1;
  block_reduce2(s, q, red);
  float mean = s * (1.f / CC);
  float var = q * (1.f / CC) - mean * mean;
  float rs = rsqrtf(var + 1e-5f);
  float2 o;
  o.x = (x0 - mean) * rs * g[c0] + be[c0];
  o.y = (x1 - mean) * rs * g[c0 + 1] + be[c0 + 1];
  *(float2*)(out + (size_t)row * CC + c0) = o;
}

// gate = sigmoid(gpre + gate_b); x1 = gate*xc + (1-gate)*ef;
// x2 = relu(LN(x1)*n1g + n1b) + xin
__global__ __launch_bounds__(256) void ln_gate_kernel(
    const float* __restrict__ gpre, const float* __restrict__ gate_b,
    const float* __restrict__ xc, const float* __restrict__ ef,
    const float* __restrict__ n1g, const float* __restrict__ n1b,
    const float* __restrict__ xin, float* __restrict__ x2) {
  int row = blockIdx.x, tid = threadIdx.x, c0 = tid * 2;
  __shared__ float red[8];
  float2 gp = *(const float2*)(gpre + (size_t)row * CC + c0);
  float2 xcv = *(const float2*)(xc + (size_t)row * CC + c0);
  float2 efv = *(const float2*)(ef + (size_t)row * CC + c0);
  float g0 = 1.f / (1.f + __expf(-(gp.x + gate_b[c0])));
  float g1 = 1.f / (1.f + __expf(-(gp.y + gate_b[c0 + 1])));
  float x0 = g0 * xcv.x + (1.f - g0) * efv.x;
  float x1 = g1 * xcv.y + (1.f - g1) * efv.y;
  float s = x0 + x1, q = x0 * x0 + x1 * x1;
  block_reduce2(s, q, red);
  float mean = s * (1.f / CC);
  float var = q * (1.f / CC) - mean * mean;
  float rs = rsqrtf(var + 1e-5f);
  float2 xi = *(const float2*)(xin + (size_t)row * CC + c0);
  float2 o;
  o.x = fmaxf((x0 - mean) * rs * n1g[c0] + n1b[c0], 0.f) + xi.x;
  o.y = fmaxf((x1 - mean) * rs * n1g[c0 + 1] + n1b[c0 + 1], 0.f) + xi.y;
  *(float2*)(x2 + (size_t)row * CC + c0) = o;
}

// ---------------- per-graph masked MHA (flash-style, thread-per-query) ------
// qkv: N x 1536 (q|k|v); graph b owns rows [gstart[b], gstart[b]+gcnt[b])
__global__ __launch_bounds__(256) void attn_kernel(const float* __restrict__ qkv,
                                                   const int* __restrict__ gstart,
                                                   const int* __restrict__ gcnt,
                                                   float* __restrict__ o) {
  int b = blockIdx.x >> 3;
  int h = blockIdx.x & 7;
  int nb = gstart[b], cnt = gcnt[b];
  int tid = threadIdx.x;
  __shared__ __align__(16) float kS[64][64];
  __shared__ __align__(16) float vS[64][64];
  const int qoff = h * 64, koff = CC + h * 64, voff = 2 * CC + h * 64;
  int niter = (cnt + 255) >> 8;
  for (int qi = 0; qi < niter; ++qi) {
    int qrow = qi * 256 + tid;
    bool qv = qrow < cnt;
    float q[64];
    if (qv) {
      const float* qp = qkv + (size_t)(nb + qrow) * (3 * CC) + qoff;
#pragma unroll
      for (int d4 = 0; d4 < 16; ++d4) {
        float4 t = *(const float4*)(qp + d4 * 4);
        q[d4 * 4 + 0] = t.x; q[d4 * 4 + 1] = t.y;
        q[d4 * 4 + 2] = t.z; q[d4 * 4 + 3] = t.w;
      }
    }
    float m = -1e30f, l = 0.f;
    float oacc[64];
#pragma unroll
    for (int d = 0; d < 64; ++d) oacc[d] = 0.f;
    for (int jb = 0; jb < cnt; jb += 64) {
      int jn = min(64, cnt - jb);
      __syncthreads();
      for (int f4 = tid; f4 < 64 * 16; f4 += 256) {
        int j = f4 >> 4;
        int d4 = (f4 & 15) << 2;
        if (j < jn) {
          const float* kp = qkv + (size_t)(nb + jb + j) * (3 * CC);
          *(float4*)(&kS[j][d4]) = *(const float4*)(kp + koff + d4);
          *(float4*)(&vS[j][d4]) = *(const float4*)(kp + voff + d4);
        }
      }
      __syncthreads();
      if (qv) {
        for (int j = 0; j < jn; ++j) {
          float s = 0.f;
#pragma unroll
          for (int d4 = 0; d4 < 16; ++d4) {
            float4 kv = *(const float4*)(&kS[j][d4 * 4]);
            s += q[d4 * 4 + 0] * kv.x + q[d4 * 4 + 1] * kv.y +
                 q[d4 * 4 + 2] * kv.z + q[d4 * 4 + 3] * kv.w;
          }
          s *= 0.125f;  // 1/sqrt(64)
          float mn = fmaxf(m, s);
          float corr = __expf(m - mn);
          float p = __expf(s - mn);
          l = l * corr + p;
          m = mn;
#pragma unroll
          for (int d4 = 0; d4 < 16; ++d4) {
            float4 vv = *(const float4*)(&vS[j][d4 * 4]);
            oacc[d4 * 4 + 0] = oacc[d4 * 4 + 0] * corr + p * vv.x;
            oacc[d4 * 4 + 1] = oacc[d4 * 4 + 1] * corr + p * vv.y;
            oacc[d4 * 4 + 2] = oacc[d4 * 4 + 2] * corr + p * vv.z;
            oacc[d4 * 4 + 3] = oacc[d4 * 4 + 3] * corr + p * vv.w;
          }
        }
      }
    }
    if (qv) {
      float inv = 1.0f / l;
      float* op = o + (size_t)(nb + qrow) * CC + qoff;
#pragma unroll
      for (int d4 = 0; d4 < 16; ++d4) {
        float4 t;
        t.x = oacc[d4 * 4 + 0] * inv;
        t.y = oacc[d4 * 4 + 1] * inv;
        t.z = oacc[d4 * 4 + 2] * inv;
        t.w = oacc[d4 * 4 + 3] * inv;
        *(float4*)(op + d4 * 4) = t;
      }
    }
  }
}

// ---------------- launch ----------------

extern "C" void kernel_launch(void* const* d_in, const int* in_sizes, int n_in,
                              void* d_out, int out_size, void* d_ws, size_t ws_size,
                              hipStream_t stream) {
  const float* x = (const float*)d_in[0];
  const float* edge_attr = (const float*)d_in[1];
  const float* gcn_w = (const float*)d_in[2];
  const float* gcn_b = (const float*)d_in[3];
  const float* ep_w = (const float*)d_in[4];
  const float* ep_b = (const float*)d_in[5];
  const float* gate_w = (const float*)d_in[6];
  const float* gate_b = (const float*)d_in[7];
  const float* n1_g = (const float*)d_in[8];
  const float* n1_b = (const float*)d_in[9];
  const float* in_w = (const float*)d_in[10];
  const float* in_b = (const float*)d_in[11];
  const float* out_w = (const float*)d_in[12];
  const float* out_b = (const float*)d_in[13];
  const float* tn_g = (const float*)d_in[14];
  const float* tn_b = (const float*)d_in[15];
  const float* m_w1 = (const float*)d_in[16];
  const float* m_b1 = (const float*)d_in[17];
  const float* m_w2 = (const float*)d_in[18];
  const float* m_b2 = (const float*)d_in[19];
  const float* fn_g = (const float*)d_in[20];
  const float* fn_b = (const float*)d_in[21];
  const int* eidx = (const int*)d_in[22];
  const int* batch = (const int*)d_in[23];
  const int* src = eidx;
  const int* dst = eidx + EE;

  // workspace layout (~208 MB)
  float* ws = (float*)d_ws;
  float* R1 = ws;                          // N*3C : qkv, later mlp hidden
  float* R2 = R1 + (size_t)NN * 3 * CC;    // N*C  : xw -> gate_pre -> o -> y
  float* R3 = R2 + (size_t)NN * CC;        // N*C  : x_conv -> x3
  float* R4 = R3 + (size_t)NN * CC;        // N*C  : ef -> o_proj
  float* ew = R4 + (size_t)NN * CC;        // E
  float* deg = ew + EE;                    // N
  float* dinv = deg + NN;                  // N
  int* ip = (int*)(dinv + NN);
  int* cnt_dst = ip;    ip += NN;
  int* start_dst = ip;  ip += NN + 1;
  int* cur_dst = ip;    ip += NN;
  int* cnt_src = ip;    ip += NN;
  int* start_src = ip;  ip += NN + 1;
  int* cur_src = ip;    ip += NN;
  int* elist_dst = ip;  ip += EE;
  int* elist_src = ip;  ip += EE;
  int* gcnt = ip;       ip += BB;
  int* gstart = ip;     ip += BB;

  float* x2 = (float*)d_out;  // x2 lives in d_out until the final LN overwrites it

  init_kernel<<<(NN + 255) / 256, 256, 0, stream>>>(deg, cnt_dst, cnt_src, gcnt);
  edge_pass1<<<(EE + 255) / 256, 256, 0, stream>>>(edge_attr, src, dst, ew, deg,
                                                   cnt_dst, cnt_src);
  node_pass<<<(NN + 255) / 256, 256, 0, stream>>>(deg, dinv, batch, gcnt);
  exscan_kernel<<<1, 1024, 0, stream>>>(cnt_dst, start_dst, cur_dst, NN);
  exscan_kernel<<<1, 1024, 0, stream>>>(cnt_src, start_src, cur_src, NN);
  gscan_kernel<<<1, 64, 0, stream>>>(gcnt, gstart);
  fill_kernel<<<(EE + 255) / 256, 256, 0, stream>>>(src, dst, cur_dst, cur_src,
                                                    elist_dst, elist_src);

  dim3 g1(CC / 64, NN / 64);
  // xw = x @ gcn_w
  gemm_kernel<0, false><<<g1, 256, 0, stream>>>(x, gcn_w, nullptr, R2, NN, CC, CC);
  xconv_kernel<<<NN, 256, 0, stream>>>(R2, ew, dinv, src, elist_dst, start_dst,
                                       gcn_b, R3);
  ef_kernel<<<NN / 8, 256, 0, stream>>>(edge_attr, ep_w, ep_b, elist_src, start_src,
                                        R4);
  // gate_pre = x_conv @ gate_w[:C] + ef @ gate_w[C:]
  gemm_kernel<0, false><<<g1, 256, 0, stream>>>(R3, gate_w, nullptr, R2, NN, CC, CC);
  gemm_kernel<0, true><<<g1, 256, 0, stream>>>(R4, gate_w + (size_t)CC * CC, nullptr,
                                               R2, NN, CC, CC);
  ln_gate_kernel<<<NN, 256, 0, stream>>>(R2, gate_b, R3, R4, n1_g, n1_b, x, x2);

  // qkv = x2 @ in_w + in_b
  dim3 g3(3 * CC / 64, NN / 64);
  gemm_kernel<0, false><<<g3, 256, 0, stream>>>(x2, in_w, in_b, R1, NN, 3 * CC, CC);
  attn_kernel<<<BB * HH, 256, 0, stream>>>(R1, gstart, gcnt, R2);
  // o_proj = o @ out_w + out_b
  gemm_kernel<0, false><<<g1, 256, 0, stream>>>(R2, out_w, out_b, R4, NN, CC, CC);
  // x3 = LN(x2 + o_proj)
  ln_add_kernel<<<NN, 256, 0, stream>>>(x2, R4, tn_g, tn_b, R3);

  // MLP: h = silu(x3 @ m_w1 + m_b1); y = h @ m_w2 + m_b2; out = LN(x3 + y)
  dim3 g5(2 * CC / 64, NN / 64);
  gemm_kernel<1, false><<<g5, 256, 0, stream>>>(R3, m_w1, m_b1, R1, NN, 2 * CC, CC);
  gemm_kernel<0, false><<<g1, 256, 0, stream>>>(R1, m_w2, m_b2, R2, NN, CC, 2 * CC);
  ln_add_kernel<<<NN, 256, 0, stream>>>(R3, R2, fn_g, fn_b, (float*)d_out);
}

// Round 2
// 1103.785 us; speedup vs baseline: 2.0180x; 2.0180x over previous
//
#include <hip/hip_runtime.h>

#define NN 16384
#define CC 512
#define EE 524288
#define BB 64
#define HH 8
#define EFD 16

typedef __bf16 bf16_t;
typedef __bf16 bf16x4 __attribute__((ext_vector_type(4)));
typedef __bf16 bf16x8 __attribute__((ext_vector_type(8)));
typedef float f32x4v __attribute__((ext_vector_type(4)));

// ---------------- init / edge pre-pass ----------------

__global__ void init_kernel(float* deg, int* cnt_dst, int* cnt_src, int* gcnt) {
  int i = blockIdx.x * 256 + threadIdx.x;
  if (i < NN) { deg[i] = 1.0f; cnt_dst[i] = 0; cnt_src[i] = 0; }
  if (i < BB) gcnt[i] = 0;
}

__global__ void edge_pass1(const float* __restrict__ ea, const int* __restrict__ src,
                           const int* __restrict__ dst, float* __restrict__ ew,
                           float* deg, int* cnt_dst, int* cnt_src) {
  int e = blockIdx.x * 256 + threadIdx.x;
  if (e >= EE) return;
  const float4* p = (const float4*)(ea + (size_t)e * EFD);
  float s = 0.f;
#pragma unroll
  for (int i = 0; i < 4; ++i) {
    float4 v = p[i];
    s += v.x * v.x + v.y * v.y + v.z * v.z + v.w * v.w;
  }
  float w = sqrtf(s);
  ew[e] = w;
  atomicAdd(&deg[dst[e]], w);
  atomicAdd(&cnt_dst[dst[e]], 1);
  atomicAdd(&cnt_src[src[e]], 1);
}

__global__ void node_pass(const float* __restrict__ deg, float* __restrict__ dinv,
                          const int* __restrict__ batch, int* gcnt) {
  int i = blockIdx.x * 256 + threadIdx.x;
  if (i >= NN) return;
  float d = deg[i];
  dinv[i] = d > 0.f ? rsqrtf(fmaxf(d, 1e-12f)) : 0.f;
  atomicAdd(&gcnt[batch[i]], 1);
}

// exclusive scan of n<=16384 ints, single block of 1024 threads (16/thread)
__global__ __launch_bounds__(1024) void exscan_kernel(const int* __restrict__ cnt,
                                                      int* __restrict__ start,
                                                      int* __restrict__ cur, int n) {
  __shared__ int sums[1024];
  int tid = threadIdx.x;
  int base = tid * 16;
  int loc[16];
  int s = 0;
#pragma unroll
  for (int k = 0; k < 16; ++k) {
    int idx = base + k;
    int v = (idx < n) ? cnt[idx] : 0;
    loc[k] = v;
    s += v;
  }
  sums[tid] = s;
  __syncthreads();
  for (int off = 1; off < 1024; off <<= 1) {
    int v = (tid >= off) ? sums[tid - off] : 0;
    __syncthreads();
    sums[tid] += v;
    __syncthreads();
  }
  int pre = (tid == 0) ? 0 : sums[tid - 1];
#pragma unroll
  for (int k = 0; k < 16; ++k) {
    int idx = base + k;
    if (idx < n) { start[idx] = pre; cur[idx] = pre; pre += loc[k]; }
  }
  if (tid == 1023) start[n] = pre;
}

__global__ void gscan_kernel(const int* __restrict__ gcnt, int* __restrict__ gstart) {
  if (threadIdx.x == 0) {
    int s = 0;
    for (int b = 0; b < BB; ++b) { gstart[b] = s; s += gcnt[b]; }
  }
}

__global__ void fill_kernel(const int* __restrict__ src, const int* __restrict__ dst,
                            int* cur_dst, int* cur_src, int* __restrict__ elist_dst,
                            int* __restrict__ elist_src) {
  int e = blockIdx.x * 256 + threadIdx.x;
  if (e >= EE) return;
  int pd = atomicAdd(&cur_dst[dst[e]], 1);
  elist_dst[pd] = e;
  int ps = atomicAdd(&cur_src[src[e]], 1);
  elist_src[ps] = e;
}

// ---------------- conversions ----------------

__global__ void cvt_bf16_kernel(const float* __restrict__ in, bf16_t* __restrict__ out,
                                int n4) {
  int i = blockIdx.x * 256 + threadIdx.x;
  if (i >= n4) return;
  float4 v = ((const float4*)in)[i];
  bf16x4 o;
  o[0] = (bf16_t)v.x; o[1] = (bf16_t)v.y; o[2] = (bf16_t)v.z; o[3] = (bf16_t)v.w;
  ((bf16x4*)out)[i] = o;
}

// W: f32 [K][N] row-major -> Wt: bf16 [N][K] row-major
__global__ __launch_bounds__(256) void wt_kernel(const float* __restrict__ W,
                                                 bf16_t* __restrict__ Wt, int K, int N) {
  __shared__ float tile[32][33];
  int bx = blockIdx.x * 32;  // N offset
  int by = blockIdx.y * 32;  // K offset
  int tx = threadIdx.x & 31, ty = threadIdx.x >> 5;  // ty 0..7
#pragma unroll
  for (int i = 0; i < 32; i += 8)
    tile[ty + i][tx] = W[(size_t)(by + ty + i) * N + bx + tx];
  __syncthreads();
#pragma unroll
  for (int i = 0; i < 32; i += 8)
    Wt[(size_t)(bx + ty + i) * K + by + tx] = (bf16_t)tile[tx][ty + i];
}

// ---------------- GCN conv gather (CSR by dst) ----------------
__global__ __launch_bounds__(256) void xconv_kernel(
    const float* __restrict__ xw, const float* __restrict__ ew,
    const float* __restrict__ dinv, const int* __restrict__ src,
    const int* __restrict__ elist, const int* __restrict__ start,
    const float* __restrict__ gcn_b, float* __restrict__ xconv,
    bf16_t* __restrict__ xcb) {
  int i = blockIdx.x;
  int tid = threadIdx.x;
  int st = start[i], en = start[i + 1];
  float di = dinv[i];
  int c0 = tid * 2;
  __shared__ int sS[256];
  __shared__ float cS[256];
  float2 xv = *(const float2*)(xw + (size_t)i * CC + c0);
  float sc = di * di;
  float a0 = sc * xv.x + gcn_b[c0];
  float a1 = sc * xv.y + gcn_b[c0 + 1];
  for (int p0 = st; p0 < en; p0 += 256) {
    int m = min(256, en - p0);
    __syncthreads();
    if (tid < m) {
      int e = elist[p0 + tid];
      int sn = src[e];
      sS[tid] = sn;
      cS[tid] = dinv[sn] * ew[e] * di;
    }
    __syncthreads();
    for (int j = 0; j < m; ++j) {
      int sn = sS[j];
      float coef = cS[j];
      float2 v = *(const float2*)(xw + (size_t)sn * CC + c0);
      a0 += coef * v.x;
      a1 += coef * v.y;
    }
  }
  *(float2*)(xconv + (size_t)i * CC + c0) = make_float2(a0, a1);
  xcb[(size_t)i * (2 * CC) + c0] = (bf16_t)a0;
  xcb[(size_t)i * (2 * CC) + c0 + 1] = (bf16_t)a1;
}

// ---------------- edge projection scatter (CSR by src) ----------------
__global__ __launch_bounds__(256) void ef_kernel(
    const float* __restrict__ ea, const float* __restrict__ ep_w,
    const float* __restrict__ ep_b, const int* __restrict__ elist,
    const int* __restrict__ start, float* __restrict__ ef, bf16_t* __restrict__ efb) {
  int tid = threadIdx.x;
  int c0 = tid * 2;
  float w0[16], w1[16];
#pragma unroll
  for (int k = 0; k < 16; ++k) {
    w0[k] = ep_w[k * CC + c0];
    w1[k] = ep_w[k * CC + c0 + 1];
  }
  float b0 = ep_b[c0], b1 = ep_b[c0 + 1];
  __shared__ float eaS[16][16];
  for (int ni = 0; ni < 8; ++ni) {
    int node = blockIdx.x * 8 + ni;
    int st = start[node], en = start[node + 1];
    float a0 = 0.f, a1 = 0.f;
    for (int p0 = st; p0 < en; p0 += 16) {
      int m = min(16, en - p0);
      __syncthreads();
      if (tid < m * 16) {
        int el = tid >> 4, ft = tid & 15;
        eaS[el][ft] = ea[(size_t)elist[p0 + el] * EFD + ft];
      }
      __syncthreads();
      for (int j = 0; j < m; ++j) {
        float t0 = b0, t1 = b1;
#pragma unroll
        for (int k = 0; k < 16; ++k) {
          float a = eaS[j][k];
          t0 += a * w0[k];
          t1 += a * w1[k];
        }
        a0 += fmaxf(t0, 0.f);
        a1 += fmaxf(t1, 0.f);
      }
    }
    ef[(size_t)node * CC + c0] = a0;
    ef[(size_t)node * CC + c0 + 1] = a1;
    efb[(size_t)node * (2 * CC) + CC + c0] = (bf16_t)a0;
    efb[(size_t)node * (2 * CC) + CC + c0 + 1] = (bf16_t)a1;
  }
}

// ---------------- bf16 MFMA GEMM (m97 structure) ----------------
// C(MxN) = A(MxK bf16 row-major) @ Bt(NxK bf16 row-major)^T [+ bias][act]
// ACT: 0=none 1=silu ; OUT: 0=f32 1=bf16
__device__ __forceinline__ void gl_lds16(const bf16_t* g, bf16_t* l) {
  __builtin_amdgcn_global_load_lds(
      (const __attribute__((address_space(1))) void*)g,
      (__attribute__((address_space(3))) void*)l, 16, 0, 0);
}

template <int ACT, int OUT>
__global__ __launch_bounds__(256) void gemm_bf16_kernel(
    const bf16_t* __restrict__ A, const bf16_t* __restrict__ Bt,
    const float* __restrict__ bias, void* __restrict__ Cout, int M, int N, int K) {
  __shared__ __align__(16) bf16_t Al[128 * 32];
  __shared__ __align__(16) bf16_t Bl[128 * 32];
  const int tid = threadIdx.x;
  const int lane = tid & 63;
  const int wave = tid >> 6;
  const int row0 = blockIdx.y * 128;
  const int col0 = blockIdx.x * 128;
  const int wm = (wave >> 1) * 64;
  const int wn = (wave & 1) * 64;
  f32x4v acc[4][4] = {};
  // staging: each thread 16B; issue i covers rows i*64 + tid/4, k = (tid%4)*8
  const bf16_t* aBase = A + (size_t)(row0 + (tid >> 2)) * K + (tid & 3) * 8;
  const bf16_t* bBase = Bt + (size_t)(col0 + (tid >> 2)) * K + (tid & 3) * 8;
  bf16_t* al0 = Al + wave * 512;
  bf16_t* al1 = Al + 2048 + wave * 512;
  bf16_t* bl0 = Bl + wave * 512;
  bf16_t* bl1 = Bl + 2048 + wave * 512;
  const int fr = lane & 15;
  const int fk = (lane >> 4) * 8;
  for (int k0 = 0; k0 < K; k0 += 32) {
    gl_lds16(aBase + k0, al0);
    gl_lds16(aBase + (size_t)64 * K + k0, al1);
    gl_lds16(bBase + k0, bl0);
    gl_lds16(bBase + (size_t)64 * K + k0, bl1);
    __syncthreads();
    bf16x8 af[4], bfv[4];
#pragma unroll
    for (int m = 0; m < 4; ++m)
      af[m] = *(const bf16x8*)(Al + (wm + m * 16 + fr) * 32 + fk);
#pragma unroll
    for (int n = 0; n < 4; ++n)
      bfv[n] = *(const bf16x8*)(Bl + (wn + n * 16 + fr) * 32 + fk);
#pragma unroll
    for (int m = 0; m < 4; ++m)
#pragma unroll
      for (int n = 0; n < 4; ++n)
        acc[m][n] =
            __builtin_amdgcn_mfma_f32_16x16x32_bf16(af[m], bfv[n], acc[m][n], 0, 0, 0);
    __syncthreads();
  }
  const int fq = (lane >> 4) * 4;
#pragma unroll
  for (int m = 0; m < 4; ++m) {
    int grb = row0 + wm + m * 16 + fq;
#pragma unroll
    for (int n = 0; n < 4; ++n) {
      int gc = col0 + wn + n * 16 + fr;
      float bv = bias ? bias[gc] : 0.f;
#pragma unroll
      for (int r = 0; r < 4; ++r) {
        float v = acc[m][n][r] + bv;
        if (ACT == 1) v = v / (1.f + __expf(-v));
        if (OUT == 0)
          ((float*)Cout)[(size_t)(grb + r) * N + gc] = v;
        else
          ((bf16_t*)Cout)[(size_t)(grb + r) * N + gc] = (bf16_t)v;
      }
    }
  }
}

// ---------------- layernorm fused kernels ----------------

__device__ inline void block_reduce2(float& s, float& q, float* red) {
#pragma unroll
  for (int off = 32; off >= 1; off >>= 1) {
    s += __shfl_xor(s, off, 64);
    q += __shfl_xor(q, off, 64);
  }
  int wid = threadIdx.x >> 6;
  if ((threadIdx.x & 63) == 0) { red[wid * 2] = s; red[wid * 2 + 1] = q; }
  __syncthreads();
  s = red[0] + red[2] + red[4] + red[6];
  q = red[1] + red[3] + red[5] + red[7];
}

// out = LN(A + B) * g + be   (+ optional bf16 copy)
__global__ __launch_bounds__(256) void ln_add_kernel(const float* __restrict__ A,
                                                     const float* __restrict__ Bb,
                                                     const float* __restrict__ g,
                                                     const float* __restrict__ be,
                                                     float* __restrict__ out,
                                                     bf16_t* __restrict__ bout) {
  int row = blockIdx.x, tid = threadIdx.x, c0 = tid * 2;
  __shared__ float red[8];
  float2 a = *(const float2*)(A + (size_t)row * CC + c0);
  float2 b = *(const float2*)(Bb + (size_t)row * CC + c0);
  float x0 = a.x + b.x, x1 = a.y + b.y;
  float s = x0 + x1, q = x0 * x0 + x1 * x1;
  block_reduce2(s, q, red);
  float mean = s * (1.f / CC);
  float var = q * (1.f / CC) - mean * mean;
  float rs = rsqrtf(var + 1e-5f);
  float o0 = (x0 - mean) * rs * g[c0] + be[c0];
  float o1 = (x1 - mean) * rs * g[c0 + 1] + be[c0 + 1];
  *(float2*)(out + (size_t)row * CC + c0) = make_float2(o0, o1);
  if (bout) {
    bout[(size_t)row * CC + c0] = (bf16_t)o0;
    bout[(size_t)row * CC + c0 + 1] = (bf16_t)o1;
  }
}

// gate+mix+LN+relu+residual; writes f32 x2 and bf16 x2b
__global__ __launch_bounds__(256) void ln_gate_kernel(
    const float* __restrict__ gpre, const float* __restrict__ gate_b,
    const float* __restrict__ xc, const float* __restrict__ ef,
    const float* __restrict__ n1g, const float* __restrict__ n1b,
    const float* __restrict__ xin, float* __restrict__ x2, bf16_t* __restrict__ x2b) {
  int row = blockIdx.x, tid = threadIdx.x, c0 = tid * 2;
  __shared__ float red[8];
  float2 gp = *(const float2*)(gpre + (size_t)row * CC + c0);
  float2 xcv = *(const float2*)(xc + (size_t)row * CC + c0);
  float2 efv = *(const float2*)(ef + (size_t)row * CC + c0);
  float g0 = 1.f / (1.f + __expf(-(gp.x + gate_b[c0])));
  float g1 = 1.f / (1.f + __expf(-(gp.y + gate_b[c0 + 1])));
  float x0 = g0 * xcv.x + (1.f - g0) * efv.x;
  float x1 = g1 * xcv.y + (1.f - g1) * efv.y;
  float s = x0 + x1, q = x0 * x0 + x1 * x1;
  block_reduce2(s, q, red);
  float mean = s * (1.f / CC);
  float var = q * (1.f / CC) - mean * mean;
  float rs = rsqrtf(var + 1e-5f);
  float2 xi = *(const float2*)(xin + (size_t)row * CC + c0);
  float o0 = fmaxf((x0 - mean) * rs * n1g[c0] + n1b[c0], 0.f) + xi.x;
  float o1 = fmaxf((x1 - mean) * rs * n1g[c0 + 1] + n1b[c0 + 1], 0.f) + xi.y;
  *(float2*)(x2 + (size_t)row * CC + c0) = make_float2(o0, o1);
  x2b[(size_t)row * CC + c0] = (bf16_t)o0;
  x2b[(size_t)row * CC + c0 + 1] = (bf16_t)o1;
}

// ---------------- per-graph masked MHA (flash-style) ----------------
__global__ __launch_bounds__(256) void attn_kernel(const float* __restrict__ qkv,
                                                   const int* __restrict__ gstart,
                                                   const int* __restrict__ gcnt,
                                                   bf16_t* __restrict__ o) {
  int b = blockIdx.x >> 3;
  int h = blockIdx.x & 7;
  int nb = gstart[b], cnt = gcnt[b];
  int tid = threadIdx.x;
  __shared__ __align__(16) float kS[64][64];
  __shared__ __align__(16) float vS[64][64];
  const int qoff = h * 64, koff = CC + h * 64, voff = 2 * CC + h * 64;
  int niter = (cnt + 255) >> 8;
  for (int qi = 0; qi < niter; ++qi) {
    int qrow = qi * 256 + tid;
    bool qv = qrow < cnt;
    float q[64];
    if (qv) {
      const float* qp = qkv + (size_t)(nb + qrow) * (3 * CC) + qoff;
#pragma unroll
      for (int d4 = 0; d4 < 16; ++d4) {
        float4 t = *(const float4*)(qp + d4 * 4);
        q[d4 * 4 + 0] = t.x; q[d4 * 4 + 1] = t.y;
        q[d4 * 4 + 2] = t.z; q[d4 * 4 + 3] = t.w;
      }
    }
    float m = -1e30f, l = 0.f;
    float oacc[64];
#pragma unroll
    for (int d = 0; d < 64; ++d) oacc[d] = 0.f;
    for (int jb = 0; jb < cnt; jb += 64) {
      int jn = min(64, cnt - jb);
      __syncthreads();
      for (int f4 = tid; f4 < 64 * 16; f4 += 256) {
        int j = f4 >> 4;
        int d4 = (f4 & 15) << 2;
        if (j < jn) {
          const float* kp = qkv + (size_t)(nb + jb + j) * (3 * CC);
          *(float4*)(&kS[j][d4]) = *(const float4*)(kp + koff + d4);
          *(float4*)(&vS[j][d4]) = *(const float4*)(kp + voff + d4);
        }
      }
      __syncthreads();
      if (qv) {
        for (int j = 0; j < jn; ++j) {
          float s = 0.f;
#pragma unroll
          for (int d4 = 0; d4 < 16; ++d4) {
            float4 kv = *(const float4*)(&kS[j][d4 * 4]);
            s += q[d4 * 4 + 0] * kv.x + q[d4 * 4 + 1] * kv.y +
                 q[d4 * 4 + 2] * kv.z + q[d4 * 4 + 3] * kv.w;
          }
          s *= 0.125f;
          float mn = fmaxf(m, s);
          float corr = __expf(m - mn);
          float p = __expf(s - mn);
          l = l * corr + p;
          m = mn;
#pragma unroll
          for (int d4 = 0; d4 < 16; ++d4) {
            float4 vv = *(const float4*)(&vS[j][d4 * 4]);
            oacc[d4 * 4 + 0] = oacc[d4 * 4 + 0] * corr + p * vv.x;
            oacc[d4 * 4 + 1] = oacc[d4 * 4 + 1] * corr + p * vv.y;
            oacc[d4 * 4 + 2] = oacc[d4 * 4 + 2] * corr + p * vv.z;
            oacc[d4 * 4 + 3] = oacc[d4 * 4 + 3] * corr + p * vv.w;
          }
        }
      }
    }
    if (qv) {
      float inv = 1.0f / l;
      bf16_t* op = o + (size_t)(nb + qrow) * CC + qoff;
#pragma unroll
      for (int d4 = 0; d4 < 16; ++d4) {
        bf16x4 t;
        t[0] = (bf16_t)(oacc[d4 * 4 + 0] * inv);
        t[1] = (bf16_t)(oacc[d4 * 4 + 1] * inv);
        t[2] = (bf16_t)(oacc[d4 * 4 + 2] * inv);
        t[3] = (bf16_t)(oacc[d4 * 4 + 3] * inv);
        *(bf16x4*)(op + d4 * 4) = t;
      }
    }
  }
}

// ---------------- launch ----------------

static inline char* alignp(char* p, size_t a) {
  return (char*)(((uintptr_t)p + a - 1) & ~(uintptr_t)(a - 1));
}

extern "C" void kernel_launch(void* const* d_in, const int* in_sizes, int n_in,
                              void* d_out, int out_size, void* d_ws, size_t ws_size,
                              hipStream_t stream) {
  const float* x = (const float*)d_in[0];
  const float* edge_attr = (const float*)d_in[1];
  const float* gcn_w = (const float*)d_in[2];
  const float* gcn_b = (const float*)d_in[3];
  const float* ep_w = (const float*)d_in[4];
  const float* ep_b = (const float*)d_in[5];
  const float* gate_w = (const float*)d_in[6];
  const float* gate_b = (const float*)d_in[7];
  const float* n1_g = (const float*)d_in[8];
  const float* n1_b = (const float*)d_in[9];
  const float* in_w = (const float*)d_in[10];
  const float* in_b = (const float*)d_in[11];
  const float* out_w = (const float*)d_in[12];
  const float* out_b = (const float*)d_in[13];
  const float* tn_g = (const float*)d_in[14];
  const float* tn_b = (const float*)d_in[15];
  const float* m_w1 = (const float*)d_in[16];
  const float* m_b1 = (const float*)d_in[17];
  const float* m_w2 = (const float*)d_in[18];
  const float* m_b2 = (const float*)d_in[19];
  const float* fn_g = (const float*)d_in[20];
  const float* fn_b = (const float*)d_in[21];
  const int* eidx = (const int*)d_in[22];
  const int* batch = (const int*)d_in[23];
  const int* src = eidx;
  const int* dst = eidx + EE;

  // workspace layout
  float* ws = (float*)d_ws;
  float* R1 = ws;                          // N*3C f32: qkv (time-shared: xb/xcef/hb)
  float* R2 = R1 + (size_t)NN * 3 * CC;    // N*C f32: xw -> gate_pre -> ob -> x3b -> y? (see below)
  float* R3 = R2 + (size_t)NN * CC;        // N*C f32: x_conv -> x3
  float* R4 = R3 + (size_t)NN * CC;        // N*C f32: ef -> o_proj -> y
  float* ew = R4 + (size_t)NN * CC;        // E
  float* deg = ew + EE;                    // N
  float* dinv = deg + NN;                  // N
  int* ip = (int*)(dinv + NN);
  int* cnt_dst = ip;    ip += NN;
  int* start_dst = ip;  ip += NN + 1;
  int* cur_dst = ip;    ip += NN;
  int* cnt_src = ip;    ip += NN;
  int* start_src = ip;  ip += NN + 1;
  int* cur_src = ip;    ip += NN;
  int* elist_dst = ip;  ip += EE;
  int* elist_src = ip;  ip += EE;
  int* gcnt = ip;       ip += BB;
  int* gstart = ip;     ip += BB;
  // dedicated bf16 region (aligned)
  char* bp = alignp((char*)ip, 64);
  bf16_t* x2b = (bf16_t*)bp;          bp += (size_t)NN * CC * 2;
  bf16_t* gcn_wt = (bf16_t*)bp;       bp += (size_t)CC * CC * 2;
  bf16_t* gate_wt = (bf16_t*)bp;      bp += (size_t)CC * 2 * CC * 2;
  bf16_t* in_wt = (bf16_t*)bp;        bp += (size_t)3 * CC * CC * 2;
  bf16_t* out_wt = (bf16_t*)bp;       bp += (size_t)CC * CC * 2;
  bf16_t* m_w1t = (bf16_t*)bp;        bp += (size_t)2 * CC * CC * 2;
  bf16_t* m_w2t = (bf16_t*)bp;        bp += (size_t)CC * 2 * CC * 2;

  // time-shared bf16 views
  bf16_t* xb = (bf16_t*)R1;      // bf16(x), dead after GEMM1
  bf16_t* xcefb = (bf16_t*)R1;   // [x_conv | ef] bf16 N x 2C, dead after gate GEMM
  bf16_t* hb = (bf16_t*)R1;      // mlp hidden bf16 N x 2C (after qkv dead)
  bf16_t* ob = (bf16_t*)R2;      // attn out bf16 (after gate_pre dead)
  bf16_t* x3b = (bf16_t*)R2;     // bf16(x3) (after ob dead)
  float* x2 = (float*)d_out;     // x2 f32 lives in d_out until final LN

  // --- edge prep ---
  init_kernel<<<(NN + 255) / 256, 256, 0, stream>>>(deg, cnt_dst, cnt_src, gcnt);
  edge_pass1<<<(EE + 255) / 256, 256, 0, stream>>>(edge_attr, src, dst, ew, deg,
                                                   cnt_dst, cnt_src);
  node_pass<<<(NN + 255) / 256, 256, 0, stream>>>(deg, dinv, batch, gcnt);
  exscan_kernel<<<1, 1024, 0, stream>>>(cnt_dst, start_dst, cur_dst, NN);
  exscan_kernel<<<1, 1024, 0, stream>>>(cnt_src, start_src, cur_src, NN);
  gscan_kernel<<<1, 64, 0, stream>>>(gcnt, gstart);
  fill_kernel<<<(EE + 255) / 256, 256, 0, stream>>>(src, dst, cur_dst, cur_src,
                                                    elist_dst, elist_src);

  // --- weight transposes (f32 [K][N] -> bf16 [N][K]) ---
  wt_kernel<<<dim3(CC / 32, CC / 32), 256, 0, stream>>>(gcn_w, gcn_wt, CC, CC);
  wt_kernel<<<dim3(CC / 32, 2 * CC / 32), 256, 0, stream>>>(gate_w, gate_wt, 2 * CC, CC);
  wt_kernel<<<dim3(3 * CC / 32, CC / 32), 256, 0, stream>>>(in_w, in_wt, CC, 3 * CC);
  wt_kernel<<<dim3(CC / 32, CC / 32), 256, 0, stream>>>(out_w, out_wt, CC, CC);
  wt_kernel<<<dim3(2 * CC / 32, CC / 32), 256, 0, stream>>>(m_w1, m_w1t, CC, 2 * CC);
  wt_kernel<<<dim3(CC / 32, 2 * CC / 32), 256, 0, stream>>>(m_w2, m_w2t, 2 * CC, CC);

  // --- GCN conv ---
  cvt_bf16_kernel<<<(NN * CC / 4 + 255) / 256, 256, 0, stream>>>(x, xb, NN * CC / 4);
  dim3 gA(CC / 128, NN / 128);
  gemm_bf16_kernel<0, 0><<<gA, 256, 0, stream>>>(xb, gcn_wt, nullptr, R2, NN, CC, CC);
  xconv_kernel<<<NN, 256, 0, stream>>>(R2, ew, dinv, src, elist_dst, start_dst,
                                       gcn_b, R3, xcefb);
  ef_kernel<<<NN / 8, 256, 0, stream>>>(edge_attr, ep_w, ep_b, elist_src, start_src,
                                        R4, xcefb);
  // gate_pre = [x_conv|ef] @ gate_w  (K=1024)
  gemm_bf16_kernel<0, 0><<<gA, 256, 0, stream>>>(xcefb, gate_wt, nullptr, R2, NN, CC,
                                                 2 * CC);
  ln_gate_kernel<<<NN, 256, 0, stream>>>(R2, gate_b, R3, R4, n1_g, n1_b, x, x2, x2b);

  // --- MHA ---
  dim3 gQ(3 * CC / 128, NN / 128);
  gemm_bf16_kernel<0, 0><<<gQ, 256, 0, stream>>>(x2b, in_wt, in_b, R1, NN, 3 * CC, CC);
  attn_kernel<<<BB * HH, 256, 0, stream>>>(R1, gstart, gcnt, ob);
  gemm_bf16_kernel<0, 0><<<gA, 256, 0, stream>>>(ob, out_wt, out_b, R4, NN, CC, CC);
  ln_add_kernel<<<NN, 256, 0, stream>>>(x2, R4, tn_g, tn_b, R3, x3b);

  // --- MLP ---
  dim3 gH(2 * CC / 128, NN / 128);
  gemm_bf16_kernel<1, 1><<<gH, 256, 0, stream>>>(x3b, m_w1t, m_b1, hb, NN, 2 * CC, CC);
  gemm_bf16_kernel<0, 0><<<gA, 256, 0, stream>>>(hb, m_w2t, m_b2, R4, NN, CC, 2 * CC);
  ln_add_kernel<<<NN, 256, 0, stream>>>(R3, R4, fn_g, fn_b, (float*)d_out, nullptr);
}

// Round 3
// 782.692 us; speedup vs baseline: 2.8459x; 1.4102x over previous
//
#include <hip/hip_runtime.h>

#define NN 16384
#define CC 512
#define EE 524288
#define BB 64
#define HH 8
#define EFD 16

typedef __bf16 bf16_t;
typedef __bf16 bf16x4 __attribute__((ext_vector_type(4)));
typedef __bf16 bf16x8 __attribute__((ext_vector_type(8)));
typedef float f32x4v __attribute__((ext_vector_type(4)));

// ---------------- init / edge pre-pass ----------------

__global__ void init_kernel(float* deg, int* cnt_dst, int* cnt_src) {
  int i = blockIdx.x * 256 + threadIdx.x;
  if (i < NN) { deg[i] = 1.0f; cnt_dst[i] = 0; cnt_src[i] = 0; }
}

__global__ void edge_pass1(const float* __restrict__ ea, const int* __restrict__ src,
                           const int* __restrict__ dst, float* __restrict__ ew,
                           float* deg, int* cnt_dst, int* cnt_src) {
  int e = blockIdx.x * 256 + threadIdx.x;
  if (e >= EE) return;
  const float4* p = (const float4*)(ea + (size_t)e * EFD);
  float s = 0.f;
#pragma unroll
  for (int i = 0; i < 4; ++i) {
    float4 v = p[i];
    s += v.x * v.x + v.y * v.y + v.z * v.z + v.w * v.w;
  }
  float w = sqrtf(s);
  ew[e] = w;
  atomicAdd(&deg[dst[e]], w);
  atomicAdd(&cnt_dst[dst[e]], 1);
  atomicAdd(&cnt_src[src[e]], 1);
}

__global__ void node_pass(const float* __restrict__ deg, float* __restrict__ dinv) {
  int i = blockIdx.x * 256 + threadIdx.x;
  if (i >= NN) return;
  float d = deg[i];
  dinv[i] = d > 0.f ? rsqrtf(fmaxf(d, 1e-12f)) : 0.f;
}

// exclusive scan of n<=16384 ints, single block of 1024 threads (16/thread)
__global__ __launch_bounds__(1024) void exscan_kernel(const int* __restrict__ cnt,
                                                      int* __restrict__ start,
                                                      int* __restrict__ cur, int n) {
  __shared__ int sums[1024];
  int tid = threadIdx.x;
  int base = tid * 16;
  int loc[16];
  int s = 0;
#pragma unroll
  for (int k = 0; k < 16; ++k) {
    int idx = base + k;
    int v = (idx < n) ? cnt[idx] : 0;
    loc[k] = v;
    s += v;
  }
  sums[tid] = s;
  __syncthreads();
  for (int off = 1; off < 1024; off <<= 1) {
    int v = (tid >= off) ? sums[tid - off] : 0;
    __syncthreads();
    sums[tid] += v;
    __syncthreads();
  }
  int pre = (tid == 0) ? 0 : sums[tid - 1];
#pragma unroll
  for (int k = 0; k < 16; ++k) {
    int idx = base + k;
    if (idx < n) { start[idx] = pre; cur[idx] = pre; pre += loc[k]; }
  }
  if (tid == 1023) start[n] = pre;
}

__global__ void fill_kernel(const int* __restrict__ src, const int* __restrict__ dst,
                            int* cur_dst, int* cur_src, int* __restrict__ elist_dst,
                            int* __restrict__ elist_src) {
  int e = blockIdx.x * 256 + threadIdx.x;
  if (e >= EE) return;
  int pd = atomicAdd(&cur_dst[dst[e]], 1);
  elist_dst[pd] = e;
  int ps = atomicAdd(&cur_src[src[e]], 1);
  elist_src[ps] = e;
}

// ---------------- conversions ----------------

__global__ void cvt_bf16_kernel(const float* __restrict__ in, bf16_t* __restrict__ out,
                                int n4) {
  int i = blockIdx.x * 256 + threadIdx.x;
  if (i >= n4) return;
  float4 v = ((const float4*)in)[i];
  bf16x4 o;
  o[0] = (bf16_t)v.x; o[1] = (bf16_t)v.y; o[2] = (bf16_t)v.z; o[3] = (bf16_t)v.w;
  ((bf16x4*)out)[i] = o;
}

// W: f32 [K][N] row-major -> Wt: bf16 [N][K] row-major
__global__ __launch_bounds__(256) void wt_kernel(const float* __restrict__ W,
                                                 bf16_t* __restrict__ Wt, int K, int N) {
  __shared__ float tile[32][33];
  int bx = blockIdx.x * 32;  // N offset
  int by = blockIdx.y * 32;  // K offset
  int tx = threadIdx.x & 31, ty = threadIdx.x >> 5;  // ty 0..7
#pragma unroll
  for (int i = 0; i < 32; i += 8)
    tile[ty + i][tx] = W[(size_t)(by + ty + i) * N + bx + tx];
  __syncthreads();
#pragma unroll
  for (int i = 0; i < 32; i += 8)
    Wt[(size_t)(bx + ty + i) * K + by + tx] = (bf16_t)tile[tx][ty + i];
}

// ---------------- GCN conv gather (CSR by dst) ----------------
__global__ __launch_bounds__(256) void xconv_kernel(
    const float* __restrict__ xw, const float* __restrict__ ew,
    const float* __restrict__ dinv, const int* __restrict__ src,
    const int* __restrict__ elist, const int* __restrict__ start,
    const float* __restrict__ gcn_b, float* __restrict__ xconv,
    bf16_t* __restrict__ xcb) {
  int i = blockIdx.x;
  int tid = threadIdx.x;
  int st = start[i], en = start[i + 1];
  float di = dinv[i];
  int c0 = tid * 2;
  __shared__ int sS[256];
  __shared__ float cS[256];
  float2 xv = *(const float2*)(xw + (size_t)i * CC + c0);
  float sc = di * di;
  float a0 = sc * xv.x + gcn_b[c0];
  float a1 = sc * xv.y + gcn_b[c0 + 1];
  for (int p0 = st; p0 < en; p0 += 256) {
    int m = min(256, en - p0);
    __syncthreads();
    if (tid < m) {
      int e = elist[p0 + tid];
      int sn = src[e];
      sS[tid] = sn;
      cS[tid] = dinv[sn] * ew[e] * di;
    }
    __syncthreads();
    for (int j = 0; j < m; ++j) {
      int sn = sS[j];
      float coef = cS[j];
      float2 v = *(const float2*)(xw + (size_t)sn * CC + c0);
      a0 += coef * v.x;
      a1 += coef * v.y;
    }
  }
  *(float2*)(xconv + (size_t)i * CC + c0) = make_float2(a0, a1);
  xcb[(size_t)i * (2 * CC) + c0] = (bf16_t)a0;
  xcb[(size_t)i * (2 * CC) + c0 + 1] = (bf16_t)a1;
}

// ---------------- edge projection scatter (CSR by src) ----------------
__global__ __launch_bounds__(256) void ef_kernel(
    const float* __restrict__ ea, const float* __restrict__ ep_w,
    const float* __restrict__ ep_b, const int* __restrict__ elist,
    const int* __restrict__ start, float* __restrict__ ef, bf16_t* __restrict__ efb) {
  int tid = threadIdx.x;
  int c0 = tid * 2;
  float w0[16], w1[16];
#pragma unroll
  for (int k = 0; k < 16; ++k) {
    w0[k] = ep_w[k * CC + c0];
    w1[k] = ep_w[k * CC + c0 + 1];
  }
  float b0 = ep_b[c0], b1 = ep_b[c0 + 1];
  __shared__ float eaS[16][16];
  for (int ni = 0; ni < 8; ++ni) {
    int node = blockIdx.x * 8 + ni;
    int st = start[node], en = start[node + 1];
    float a0 = 0.f, a1 = 0.f;
    for (int p0 = st; p0 < en; p0 += 16) {
      int m = min(16, en - p0);
      __syncthreads();
      if (tid < m * 16) {
        int el = tid >> 4, ft = tid & 15;
        eaS[el][ft] = ea[(size_t)elist[p0 + el] * EFD + ft];
      }
      __syncthreads();
      for (int j = 0; j < m; ++j) {
        float t0 = b0, t1 = b1;
#pragma unroll
        for (int k = 0; k < 16; ++k) {
          float a = eaS[j][k];
          t0 += a * w0[k];
          t1 += a * w1[k];
        }
        a0 += fmaxf(t0, 0.f);
        a1 += fmaxf(t1, 0.f);
      }
    }
    ef[(size_t)node * CC + c0] = a0;
    ef[(size_t)node * CC + c0 + 1] = a1;
    efb[(size_t)node * (2 * CC) + CC + c0] = (bf16_t)a0;
    efb[(size_t)node * (2 * CC) + CC + c0 + 1] = (bf16_t)a1;
  }
}

// ---------------- bf16 MFMA GEMM (m97 structure) ----------------
__device__ __forceinline__ void gl_lds16(const bf16_t* g, bf16_t* l) {
  __builtin_amdgcn_global_load_lds(
      (const __attribute__((address_space(1))) void*)g,
      (__attribute__((address_space(3))) void*)l, 16, 0, 0);
}

template <int ACT, int OUT>
__global__ __launch_bounds__(256) void gemm_bf16_kernel(
    const bf16_t* __restrict__ A, const bf16_t* __restrict__ Bt,
    const float* __restrict__ bias, void* __restrict__ Cout, int M, int N, int K) {
  __shared__ __align__(16) bf16_t Al[128 * 32];
  __shared__ __align__(16) bf16_t Bl[128 * 32];
  const int tid = threadIdx.x;
  const int lane = tid & 63;
  const int wave = tid >> 6;
  const int row0 = blockIdx.y * 128;
  const int col0 = blockIdx.x * 128;
  const int wm = (wave >> 1) * 64;
  const int wn = (wave & 1) * 64;
  f32x4v acc[4][4] = {};
  const bf16_t* aBase = A + (size_t)(row0 + (tid >> 2)) * K + (tid & 3) * 8;
  const bf16_t* bBase = Bt + (size_t)(col0 + (tid >> 2)) * K + (tid & 3) * 8;
  bf16_t* al0 = Al + wave * 512;
  bf16_t* al1 = Al + 2048 + wave * 512;
  bf16_t* bl0 = Bl + wave * 512;
  bf16_t* bl1 = Bl + 2048 + wave * 512;
  const int fr = lane & 15;
  const int fk = (lane >> 4) * 8;
  for (int k0 = 0; k0 < K; k0 += 32) {
    gl_lds16(aBase + k0, al0);
    gl_lds16(aBase + (size_t)64 * K + k0, al1);
    gl_lds16(bBase + k0, bl0);
    gl_lds16(bBase + (size_t)64 * K + k0, bl1);
    __syncthreads();
    bf16x8 af[4], bfv[4];
#pragma unroll
    for (int m = 0; m < 4; ++m)
      af[m] = *(const bf16x8*)(Al + (wm + m * 16 + fr) * 32 + fk);
#pragma unroll
    for (int n = 0; n < 4; ++n)
      bfv[n] = *(const bf16x8*)(Bl + (wn + n * 16 + fr) * 32 + fk);
#pragma unroll
    for (int m = 0; m < 4; ++m)
#pragma unroll
      for (int n = 0; n < 4; ++n)
        acc[m][n] =
            __builtin_amdgcn_mfma_f32_16x16x32_bf16(af[m], bfv[n], acc[m][n], 0, 0, 0);
    __syncthreads();
  }
  const int fq = (lane >> 4) * 4;
#pragma unroll
  for (int m = 0; m < 4; ++m) {
    int grb = row0 + wm + m * 16 + fq;
#pragma unroll
    for (int n = 0; n < 4; ++n) {
      int gc = col0 + wn + n * 16 + fr;
      float bv = bias ? bias[gc] : 0.f;
#pragma unroll
      for (int r = 0; r < 4; ++r) {
        float v = acc[m][n][r] + bv;
        if (ACT == 1) v = v / (1.f + __expf(-v));
        if (OUT == 0)
          ((float*)Cout)[(size_t)(grb + r) * N + gc] = v;
        else
          ((bf16_t*)Cout)[(size_t)(grb + r) * N + gc] = (bf16_t)v;
      }
    }
  }
}

// ---------------- layernorm fused kernels ----------------

__device__ inline void block_reduce2(float& s, float& q, float* red) {
#pragma unroll
  for (int off = 32; off >= 1; off >>= 1) {
    s += __shfl_xor(s, off, 64);
    q += __shfl_xor(q, off, 64);
  }
  int wid = threadIdx.x >> 6;
  if ((threadIdx.x & 63) == 0) { red[wid * 2] = s; red[wid * 2 + 1] = q; }
  __syncthreads();
  s = red[0] + red[2] + red[4] + red[6];
  q = red[1] + red[3] + red[5] + red[7];
}

__global__ __launch_bounds__(256) void ln_add_kernel(const float* __restrict__ A,
                                                     const float* __restrict__ Bb,
                                                     const float* __restrict__ g,
                                                     const float* __restrict__ be,
                                                     float* __restrict__ out,
                                                     bf16_t* __restrict__ bout) {
  int row = blockIdx.x, tid = threadIdx.x, c0 = tid * 2;
  __shared__ float red[8];
  float2 a = *(const float2*)(A + (size_t)row * CC + c0);
  float2 b = *(const float2*)(Bb + (size_t)row * CC + c0);
  float x0 = a.x + b.x, x1 = a.y + b.y;
  float s = x0 + x1, q = x0 * x0 + x1 * x1;
  block_reduce2(s, q, red);
  float mean = s * (1.f / CC);
  float var = q * (1.f / CC) - mean * mean;
  float rs = rsqrtf(var + 1e-5f);
  float o0 = (x0 - mean) * rs * g[c0] + be[c0];
  float o1 = (x1 - mean) * rs * g[c0 + 1] + be[c0 + 1];
  *(float2*)(out + (size_t)row * CC + c0) = make_float2(o0, o1);
  if (bout) {
    bout[(size_t)row * CC + c0] = (bf16_t)o0;
    bout[(size_t)row * CC + c0 + 1] = (bf16_t)o1;
  }
}

__global__ __launch_bounds__(256) void ln_gate_kernel(
    const float* __restrict__ gpre, const float* __restrict__ gate_b,
    const float* __restrict__ xc, const float* __restrict__ ef,
    const float* __restrict__ n1g, const float* __restrict__ n1b,
    const float* __restrict__ xin, float* __restrict__ x2, bf16_t* __restrict__ x2b) {
  int row = blockIdx.x, tid = threadIdx.x, c0 = tid * 2;
  __shared__ float red[8];
  float2 gp = *(const float2*)(gpre + (size_t)row * CC + c0);
  float2 xcv = *(const float2*)(xc + (size_t)row * CC + c0);
  float2 efv = *(const float2*)(ef + (size_t)row * CC + c0);
  float g0 = 1.f / (1.f + __expf(-(gp.x + gate_b[c0])));
  float g1 = 1.f / (1.f + __expf(-(gp.y + gate_b[c0 + 1])));
  float x0 = g0 * xcv.x + (1.f - g0) * efv.x;
  float x1 = g1 * xcv.y + (1.f - g1) * efv.y;
  float s = x0 + x1, q = x0 * x0 + x1 * x1;
  block_reduce2(s, q, red);
  float mean = s * (1.f / CC);
  float var = q * (1.f / CC) - mean * mean;
  float rs = rsqrtf(var + 1e-5f);
  float2 xi = *(const float2*)(xin + (size_t)row * CC + c0);
  float o0 = fmaxf((x0 - mean) * rs * n1g[c0] + n1b[c0], 0.f) + xi.x;
  float o1 = fmaxf((x1 - mean) * rs * n1g[c0 + 1] + n1b[c0 + 1], 0.f) + xi.y;
  *(float2*)(x2 + (size_t)row * CC + c0) = make_float2(o0, o1);
  x2b[(size_t)row * CC + c0] = (bf16_t)o0;
  x2b[(size_t)row * CC + c0 + 1] = (bf16_t)o1;
}

// ---------------- V^T pack (pre-swizzled for attn LDS) ----------------
// vt[bh] bytes laid out as attn LDS: byte(d,k) = d*512 + ((k*2) ^ ((d&7)<<4))
__global__ __launch_bounds__(256) void vt_pack_kernel(const bf16_t* __restrict__ qkvb,
                                                      bf16_t* __restrict__ vt) {
  int b = blockIdx.x >> 3, h = blockIdx.x & 7;
  int nb = b * 256;
  size_t voff = 1024 + (size_t)h * 64;
  char* out = (char*)(vt + (size_t)blockIdx.x * (64 * 256));
  __shared__ bf16_t tile[64][80];  // [k][d], 160B rows (16B aligned)
  int tid = threadIdx.x;
  for (int kb = 0; kb < 4; ++kb) {
    __syncthreads();
#pragma unroll
    for (int p = 0; p < 2; ++p) {
      int k = p * 32 + (tid >> 3);
      int d8 = tid & 7;
      bf16x8 v = *(const bf16x8*)(qkvb + (size_t)(nb + kb * 64 + k) * 1536 + voff + d8 * 8);
      *(bf16x8*)(&tile[k][d8 * 8]) = v;
    }
    __syncthreads();
#pragma unroll
    for (int p = 0; p < 2; ++p) {
      int d = p * 32 + (tid >> 3);
      int k8 = tid & 7;
      bf16x8 v;
#pragma unroll
      for (int j = 0; j < 8; ++j) v[j] = tile[k8 * 8 + j][d];
      int byteoff = d * 512 + ((kb * 128 + k8 * 16) ^ ((d & 7) << 4));
      *(bf16x8*)(out + byteoff) = v;
    }
  }
}

// ---------------- MFMA attention: one block per (b,h), 4 waves x 64 q-rows --
__global__ __launch_bounds__(256, 2) void attn_mfma_kernel(
    const bf16_t* __restrict__ qkvb, const bf16_t* __restrict__ vt,
    bf16_t* __restrict__ o) {
  const int b = blockIdx.x >> 3;
  const int h = blockIdx.x & 7;
  const int nb = b * 256;
  const int tid = threadIdx.x;
  const int lane = tid & 63;
  const int wv = tid >> 6;
  const int l15 = lane & 15;
  const int g = lane >> 4;
  const int swzk = (l15 & 7) << 4;  // byte XOR for frag reads (row&7 == l15&7)
  __shared__ __align__(16) bf16_t Klds[256 * 64];   // swizzled [k][d] 32KB
  __shared__ __align__(16) bf16_t Vtlds[64 * 256];  // swizzled [d][k] 32KB
  const size_t qoff = (size_t)h * 64;
  const size_t koff = 512 + (size_t)h * 64;

  // ---- stage K: LDS byte L = (i*256+tid)*16; k=i*32+(tid>>3); swizzled src col
  {
    const int dcol = 16 * ((tid & 7) ^ ((tid >> 3) & 7));  // byte within row
    const bf16_t* srcb = qkvb + koff + (dcol >> 1);
#pragma unroll
    for (int i = 0; i < 8; ++i) {
      int k = i * 32 + (tid >> 3);
      gl_lds16(srcb + (size_t)(nb + k) * 1536, Klds + ((i * 4096 + wv * 1024) >> 1));
    }
  }
  // ---- stage Vt (already swizzle-packed): linear copy
  {
    const bf16_t* vsrc = vt + (size_t)blockIdx.x * (64 * 256);
#pragma unroll
    for (int i = 0; i < 8; ++i) {
      int base = i * 4096 + wv * 1024;  // bytes
      gl_lds16(vsrc + ((base >> 1) + lane * 8), Vtlds + (base >> 1));
    }
  }

  // ---- Q fragments in regs: qf[n][h2] = Q[wv*64+16n+l15][32*h2+8g .. +7]
  bf16x8 qf[4][2];
#pragma unroll
  for (int n = 0; n < 4; ++n) {
    const bf16_t* qp = qkvb + (size_t)(nb + wv * 64 + 16 * n + l15) * 1536 + qoff + g * 8;
    qf[n][0] = *(const bf16x8*)(qp);
    qf[n][1] = *(const bf16x8*)(qp + 32);
  }

  __syncthreads();

  f32x4v oacc[4][4] = {};  // Ot: [m: d-tiles][n: q-tiles]
  float mrun[4] = {-1e30f, -1e30f, -1e30f, -1e30f};
  float lrun[4] = {0.f, 0.f, 0.f, 0.f};
  const int srcA = ((g & 1) << 5) | l15;
  const int srcB = srcA | 16;

  for (int kc = 0; kc < 4; ++kc) {
    // ---- St = K . Q^T : D[k][q]
    f32x4v sacc[4][4] = {};
    const int kb128 = (kc * 64 + l15) * 128;
#pragma unroll
    for (int m = 0; m < 4; ++m) {
      bf16x8 a0 = *(const bf16x8*)(Klds + ((kb128 + m * 2048 + ((g * 16) ^ swzk)) >> 1));
      bf16x8 a1 =
          *(const bf16x8*)(Klds + ((kb128 + m * 2048 + ((64 + g * 16) ^ swzk)) >> 1));
#pragma unroll
      for (int n = 0; n < 4; ++n) {
        sacc[m][n] = __builtin_amdgcn_mfma_f32_16x16x32_bf16(a0, qf[n][0], sacc[m][n], 0, 0, 0);
        sacc[m][n] = __builtin_amdgcn_mfma_f32_16x16x32_bf16(a1, qf[n][1], sacc[m][n], 0, 0, 0);
      }
    }
    // ---- online softmax (scale 0.125 folded into exp)
    uint2 pb[4][4];
#pragma unroll
    for (int n = 0; n < 4; ++n) {
      float mx = sacc[0][n][0];
#pragma unroll
      for (int m = 0; m < 4; ++m)
#pragma unroll
        for (int r = 0; r < 4; ++r) mx = fmaxf(mx, sacc[m][n][r]);
      mx = fmaxf(mx, __shfl_xor(mx, 16));
      mx = fmaxf(mx, __shfl_xor(mx, 32));
      float mnew = fmaxf(mrun[n], mx);
      float c = __expf((mrun[n] - mnew) * 0.125f);
      mrun[n] = mnew;
      float s = 0.f;
#pragma unroll
      for (int m = 0; m < 4; ++m) {
        float p0 = __expf((sacc[m][n][0] - mnew) * 0.125f);
        float p1 = __expf((sacc[m][n][1] - mnew) * 0.125f);
        float p2 = __expf((sacc[m][n][2] - mnew) * 0.125f);
        float p3 = __expf((sacc[m][n][3] - mnew) * 0.125f);
        s += (p0 + p1) + (p2 + p3);
        union { bf16x4 v; uint2 u; } cv;
        cv.v[0] = (bf16_t)p0; cv.v[1] = (bf16_t)p1;
        cv.v[2] = (bf16_t)p2; cv.v[3] = (bf16_t)p3;
        pb[m][n] = cv.u;
      }
      s += __shfl_xor(s, 16);
      s += __shfl_xor(s, 32);
      lrun[n] = lrun[n] * c + s;
#pragma unroll
      for (int m = 0; m < 4; ++m)
#pragma unroll
        for (int r = 0; r < 4; ++r) oacc[m][n][r] *= c;
    }
    // ---- PV: Ot += Vt . Pt
#pragma unroll
    for (int h2 = 0; h2 < 2; ++h2) {
      bf16x8 vf[4];
#pragma unroll
      for (int m = 0; m < 4; ++m)
        vf[m] = *(const bf16x8*)(Vtlds + (((16 * m + l15) * 512 +
                                          ((kc * 128 + h2 * 64 + g * 16) ^ swzk)) >> 1));
#pragma unroll
      for (int n = 0; n < 4; ++n) {
        int a0 = __shfl((int)pb[2 * h2][n].x, srcA);
        int b0 = __shfl((int)pb[2 * h2 + 1][n].x, srcA);
        int a1 = __shfl((int)pb[2 * h2][n].y, srcA);
        int b1 = __shfl((int)pb[2 * h2 + 1][n].y, srcA);
        int a2 = __shfl((int)pb[2 * h2][n].x, srcB);
        int b2 = __shfl((int)pb[2 * h2 + 1][n].x, srcB);
        int a3 = __shfl((int)pb[2 * h2][n].y, srcB);
        int b3 = __shfl((int)pb[2 * h2 + 1][n].y, srcB);
        union { int u[4]; bf16x8 v; } pf;
        bool hi = (g >= 2);
        pf.u[0] = hi ? b0 : a0;
        pf.u[1] = hi ? b1 : a1;
        pf.u[2] = hi ? b2 : a2;
        pf.u[3] = hi ? b3 : a3;
#pragma unroll
        for (int m = 0; m < 4; ++m)
          oacc[m][n] =
              __builtin_amdgcn_mfma_f32_16x16x32_bf16(vf[m], pf.v, oacc[m][n], 0, 0, 0);
      }
    }
  }
  // ---- store O: Ot[d=16m+4g+r][q=16n+l15] -> o[row=q][h*64+d], packed over r
  float inv[4];
#pragma unroll
  for (int n = 0; n < 4; ++n) inv[n] = 1.0f / lrun[n];
#pragma unroll
  for (int m = 0; m < 4; ++m)
#pragma unroll
    for (int n = 0; n < 4; ++n) {
      bf16x4 pk;
#pragma unroll
      for (int r = 0; r < 4; ++r) pk[r] = (bf16_t)(oacc[m][n][r] * inv[n]);
      *(bf16x4*)(o + (size_t)(nb + wv * 64 + 16 * n + l15) * 512 + h * 64 + 16 * m +
                 4 * g) = pk;
    }
}

// ---------------- launch ----------------

static inline char* alignp(char* p, size_t a) {
  return (char*)(((uintptr_t)p + a - 1) & ~(uintptr_t)(a - 1));
}

extern "C" void kernel_launch(void* const* d_in, const int* in_sizes, int n_in,
                              void* d_out, int out_size, void* d_ws, size_t ws_size,
                              hipStream_t stream) {
  const float* x = (const float*)d_in[0];
  const float* edge_attr = (const float*)d_in[1];
  const float* gcn_w = (const float*)d_in[2];
  const float* gcn_b = (const float*)d_in[3];
  const float* ep_w = (const float*)d_in[4];
  const float* ep_b = (const float*)d_in[5];
  const float* gate_w = (const float*)d_in[6];
  const float* gate_b = (const float*)d_in[7];
  const float* n1_g = (const float*)d_in[8];
  const float* n1_b = (const float*)d_in[9];
  const float* in_w = (const float*)d_in[10];
  const float* in_b = (const float*)d_in[11];
  const float* out_w = (const float*)d_in[12];
  const float* out_b = (const float*)d_in[13];
  const float* tn_g = (const float*)d_in[14];
  const float* tn_b = (const float*)d_in[15];
  const float* m_w1 = (const float*)d_in[16];
  const float* m_b1 = (const float*)d_in[17];
  const float* m_w2 = (const float*)d_in[18];
  const float* m_b2 = (const float*)d_in[19];
  const float* fn_g = (const float*)d_in[20];
  const float* fn_b = (const float*)d_in[21];
  const int* eidx = (const int*)d_in[22];
  const int* src = eidx;
  const int* dst = eidx + EE;

  float* ws = (float*)d_ws;
  float* R1 = ws;                          // N*3C f32 region (time-shared bf16 views)
  float* R2 = R1 + (size_t)NN * 3 * CC;    // N*C f32: xw -> gate_pre -> [ob|vt] -> x3b
  float* R3 = R2 + (size_t)NN * CC;        // N*C f32: x_conv -> x3
  float* R4 = R3 + (size_t)NN * CC;        // N*C f32: ef -> o_proj -> y
  float* ew = R4 + (size_t)NN * CC;        // E
  float* deg = ew + EE;                    // N
  float* dinv = deg + NN;                  // N
  int* ip = (int*)(dinv + NN);
  int* cnt_dst = ip;    ip += NN;
  int* start_dst = ip;  ip += NN + 1;
  int* cur_dst = ip;    ip += NN;
  int* cnt_src = ip;    ip += NN;
  int* start_src = ip;  ip += NN + 1;
  int* cur_src = ip;    ip += NN;
  int* elist_dst = ip;  ip += EE;
  int* elist_src = ip;  ip += EE;
  char* bp = alignp((char*)ip, 64);
  bf16_t* x2b = (bf16_t*)bp;          bp += (size_t)NN * CC * 2;
  bf16_t* gcn_wt = (bf16_t*)bp;       bp += (size_t)CC * CC * 2;
  bf16_t* gate_wt = (bf16_t*)bp;      bp += (size_t)CC * 2 * CC * 2;
  bf16_t* in_wt = (bf16_t*)bp;        bp += (size_t)3 * CC * CC * 2;
  bf16_t* out_wt = (bf16_t*)bp;       bp += (size_t)CC * CC * 2;
  bf16_t* m_w1t = (bf16_t*)bp;        bp += (size_t)2 * CC * CC * 2;
  bf16_t* m_w2t = (bf16_t*)bp;        bp += (size_t)CC * 2 * CC * 2;

  bf16_t* xb = (bf16_t*)R1;      // bf16(x)
  bf16_t* xcefb = (bf16_t*)R1;   // [x_conv | ef] bf16 N x 2C
  bf16_t* qkvb = (bf16_t*)R1;    // qkv bf16 N x 1536 (50MB of R1's 100MB)
  bf16_t* hb = (bf16_t*)R1;      // mlp hidden bf16 N x 2C
  bf16_t* ob = (bf16_t*)R2;                  // attn out bf16 (first half of R2)
  bf16_t* vt = ob + (size_t)NN * CC;         // V^T packed (second half of R2)
  bf16_t* x3b = (bf16_t*)R2;                 // bf16(x3) (after ob dead)
  float* x2 = (float*)d_out;

  // --- edge prep ---
  init_kernel<<<(NN + 255) / 256, 256, 0, stream>>>(deg, cnt_dst, cnt_src);
  edge_pass1<<<(EE + 255) / 256, 256, 0, stream>>>(edge_attr, src, dst, ew, deg,
                                                   cnt_dst, cnt_src);
  node_pass<<<(NN + 255) / 256, 256, 0, stream>>>(deg, dinv);
  exscan_kernel<<<1, 1024, 0, stream>>>(cnt_dst, start_dst, cur_dst, NN);
  exscan_kernel<<<1, 1024, 0, stream>>>(cnt_src, start_src, cur_src, NN);
  fill_kernel<<<(EE + 255) / 256, 256, 0, stream>>>(src, dst, cur_dst, cur_src,
                                                    elist_dst, elist_src);

  // --- weight transposes ---
  wt_kernel<<<dim3(CC / 32, CC / 32), 256, 0, stream>>>(gcn_w, gcn_wt, CC, CC);
  wt_kernel<<<dim3(CC / 32, 2 * CC / 32), 256, 0, stream>>>(gate_w, gate_wt, 2 * CC, CC);
  wt_kernel<<<dim3(3 * CC / 32, CC / 32), 256, 0, stream>>>(in_w, in_wt, CC, 3 * CC);
  wt_kernel<<<dim3(CC / 32, CC / 32), 256, 0, stream>>>(out_w, out_wt, CC, CC);
  wt_kernel<<<dim3(2 * CC / 32, CC / 32), 256, 0, stream>>>(m_w1, m_w1t, CC, 2 * CC);
  wt_kernel<<<dim3(CC / 32, 2 * CC / 32), 256, 0, stream>>>(m_w2, m_w2t, 2 * CC, CC);

  // --- GCN conv ---
  cvt_bf16_kernel<<<(NN * CC / 4 + 255) / 256, 256, 0, stream>>>(x, xb, NN * CC / 4);
  dim3 gA(CC / 128, NN / 128);
  gemm_bf16_kernel<0, 0><<<gA, 256, 0, stream>>>(xb, gcn_wt, nullptr, R2, NN, CC, CC);
  xconv_kernel<<<NN, 256, 0, stream>>>(R2, ew, dinv, src, elist_dst, start_dst,
                                       gcn_b, R3, xcefb);
  ef_kernel<<<NN / 8, 256, 0, stream>>>(edge_attr, ep_w, ep_b, elist_src, start_src,
                                        R4, xcefb);
  gemm_bf16_kernel<0, 0><<<gA, 256, 0, stream>>>(xcefb, gate_wt, nullptr, R2, NN, CC,
                                                 2 * CC);
  ln_gate_kernel<<<NN, 256, 0, stream>>>(R2, gate_b, R3, R4, n1_g, n1_b, x, x2, x2b);

  // --- MHA ---
  dim3 gQ(3 * CC / 128, NN / 128);
  gemm_bf16_kernel<0, 1><<<gQ, 256, 0, stream>>>(x2b, in_wt, in_b, qkvb, NN, 3 * CC, CC);
  vt_pack_kernel<<<BB * HH, 256, 0, stream>>>(qkvb, vt);
  attn_mfma_kernel<<<BB * HH, 256, 0, stream>>>(qkvb, vt, ob);
  gemm_bf16_kernel<0, 0><<<gA, 256, 0, stream>>>(ob, out_wt, out_b, R4, NN, CC, CC);
  ln_add_kernel<<<NN, 256, 0, stream>>>(x2, R4, tn_g, tn_b, R3, x3b);

  // --- MLP ---
  dim3 gH(2 * CC / 128, NN / 128);
  gemm_bf16_kernel<1, 1><<<gH, 256, 0, stream>>>(x3b, m_w1t, m_b1, hb, NN, 2 * CC, CC);
  gemm_bf16_kernel<0, 0><<<gA, 256, 0, stream>>>(hb, m_w2t, m_b2, R4, NN, CC, 2 * CC);
  ln_add_kernel<<<NN, 256, 0, stream>>>(R3, R4, fn_g, fn_b, (float*)d_out, nullptr);
}